// Round 1
// baseline (858.497 us; speedup 1.0000x reference)
//
#include <hip/hip_runtime.h>
#include <hip/hip_bf16.h>

#define CH 8
#define SEC 32768
#define FIN 64
#define FOUT 64
#define UN 512
#define BM 64

typedef __bf16 bf16;
typedef bf16 bf16x8 __attribute__((ext_vector_type(8)));
typedef bf16 bf16x4 __attribute__((ext_vector_type(4)));
typedef float f32x4 __attribute__((ext_vector_type(4)));

// async global->LDS, 16B per lane; LDS dest is wave-uniform base + lane*16
__device__ __forceinline__ void gload_lds16(const void* g, void* l) {
  __builtin_amdgcn_global_load_lds(
      (const __attribute__((address_space(1))) void*)g,
      (__attribute__((address_space(3))) void*)l, 16, 0, 0);
}

// load 8 consecutive fp32, convert to bf16x8, store 16B to LDS
__device__ __forceinline__ void store_cvt8(void* dst, const float* __restrict__ src) {
  f32x4 u0 = *(const f32x4*)src;
  f32x4 u1 = *(const f32x4*)(src + 4);
  bf16x8 v;
  v[0] = (bf16)u0[0]; v[1] = (bf16)u0[1]; v[2] = (bf16)u0[2]; v[3] = (bf16)u0[3];
  v[4] = (bf16)u1[0]; v[5] = (bf16)u1[1]; v[6] = (bf16)u1[2]; v[7] = (bf16)u1[3];
  *(bf16x8*)dst = v;
}

// One layer: [64 x K] (LDS, frag order) x [N x K]^T (global bf16/fp32) -> [64 x N]
// Wave (wm = w&1, wn = w>>1): rows wm*32..+31, cols wn*(N/4)..  (N=512) or wn*16 (N=64)
template<int K, int N, bool WSPATH>
__device__ __forceinline__ void run_layer(
    const bf16* __restrict__ wb, const float* __restrict__ wf,
    const float* __restrict__ bias,
    const char* __restrict__ actIn, char* __restrict__ actOut,
    float* __restrict__ gout, char* __restrict__ wst,
    int w, int l, int l15, int l4, int wm, int wn)
{
  constexpr int NKS = K / 32;            // k-steps
  constexpr int NTW = (N == 512) ? 8 : 1; // n-tiles per wave
  constexpr bool FINAL = (N == 64);

  f32x4 acc[2][NTW];
#pragma unroll
  for (int mt = 0; mt < 2; ++mt)
#pragma unroll
    for (int nt = 0; nt < NTW; ++nt)
      acc[mt][nt] = f32x4{0.f, 0.f, 0.f, 0.f};

  for (int ks = 0; ks < NKS; ++ks) {
    // ---- stage weight k-panel into LDS in fragment order ----
    if constexpr (!FINAL) {
#pragma unroll
      for (int i = 0; i < 4; ++i) {
        const int f = w * 4 + i;  // global n-tile
        if constexpr (WSPATH) {
          gload_lds16(wb + (size_t)(f * 16 + l15) * K + ks * 32 + l4 * 8,
                      wst + f * 1024);
        } else {
          store_cvt8(wst + f * 1024 + l * 16,
                     wf + (size_t)(f * 16 + l15) * K + ks * 32 + l4 * 8);
        }
      }
    } else {
      if (w < 4) {
        const int f = w;
        if constexpr (WSPATH) {
          gload_lds16(wb + (size_t)(f * 16 + l15) * K + ks * 32 + l4 * 8,
                      wst + f * 1024);
        } else {
          store_cvt8(wst + f * 1024 + l * 16,
                     wf + (size_t)(f * 16 + l15) * K + ks * 32 + l4 * 8);
        }
      }
    }
    __syncthreads();  // staging visible (compiler drains vmcnt/lgkmcnt)

    const bf16x8 a0 = *(const bf16x8*)(actIn + ((wm * 2 + 0) * NKS + ks) * 1024 + l * 16);
    const bf16x8 a1 = *(const bf16x8*)(actIn + ((wm * 2 + 1) * NKS + ks) * 1024 + l * 16);
#pragma unroll
    for (int nt = 0; nt < NTW; ++nt) {
      const bf16x8 b = *(const bf16x8*)(wst + (wn * NTW + nt) * 1024 + l * 16);
      acc[0][nt] = __builtin_amdgcn_mfma_f32_16x16x32_bf16(a0, b, acc[0][nt], 0, 0, 0);
      acc[1][nt] = __builtin_amdgcn_mfma_f32_16x16x32_bf16(a1, b, acc[1][nt], 0, 0, 0);
    }
    __syncthreads();  // protect wstage before next k-panel overwrite
  }

  // ---- epilogue: bias (+relu) -> actOut in next layer's frag order (nk=16) ----
  if constexpr (!FINAL) {
#pragma unroll
    for (int mt = 0; mt < 2; ++mt) {
      const int base0 = (wm * 2 + mt) * 16384 + l4 * 64;  // mtile*16*1024 + (l4*4)*16
#pragma unroll
      for (int nt = 0; nt < NTW; ++nt) {
        const int col = wn * 128 + nt * 16 + l15;  // = next layer's k
        const float bv = bias[col];
        const int addr = base0 + (col >> 5) * 1024 + ((col >> 3) & 3) * 256 + (col & 7) * 2;
#pragma unroll
        for (int r = 0; r < 4; ++r) {
          float v = acc[mt][nt][r] + bv;
          v = v > 0.f ? v : 0.f;
          *(bf16*)(actOut + addr + r * 16) = (bf16)v;
        }
      }
    }
  } else {
    const int col = wn * 16 + l15;
    const float bv = bias[col];
#pragma unroll
    for (int mt = 0; mt < 2; ++mt) {
      const int rowl = wm * 32 + mt * 16 + l4 * 4;
#pragma unroll
      for (int r = 0; r < 4; ++r)
        gout[(size_t)(rowl + r) * FOUT + col] = acc[mt][0][r] + bv;  // no relu on final
    }
  }
}

template<bool WSPATH>
__global__ __launch_bounds__(512, 2) void mlp_fused(
    const float* __restrict__ x,
    const float* __restrict__ w0f, const float* __restrict__ w1f,
    const float* __restrict__ w2f, const float* __restrict__ w3f,
    const float* __restrict__ b0, const float* __restrict__ b1,
    const float* __restrict__ b2, const float* __restrict__ b3,
    const bf16* __restrict__ wbase,
    float* __restrict__ out)
{
  extern __shared__ char smem[];
  char* actA = smem;            // 64 KiB: [4 mtiles][nk][64 lanes][16B]
  char* actB = smem + 65536;    // 64 KiB
  char* wst  = smem + 131072;   // 32 KiB: [32 frags][64 lanes][16B]

  const int tid = threadIdx.x;
  const int w = tid >> 6, l = tid & 63;
  const int l15 = l & 15, l4 = l >> 4;
  const int wm = w & 1, wn = w >> 1;

  // XCD-chunked swizzle: each XCD owns one channel -> weights L2-resident
  const int wg = (blockIdx.x & 7) * 512 + (blockIdx.x >> 3);
  const int ch = wg >> 9;
  const int row0 = (wg & 511) * BM;

  const bf16* w0b = wbase + (size_t)ch * UN * FIN;
  const bf16* w1b = wbase + CH * UN * FIN + (size_t)ch * UN * UN;
  const bf16* w2b = wbase + CH * UN * FIN + CH * UN * UN + (size_t)ch * UN * UN;
  const bf16* w3b = wbase + CH * UN * FIN + 2 * CH * UN * UN + (size_t)ch * FOUT * UN;
  const float* w0c = w0f + (size_t)ch * UN * FIN;
  const float* w1c = w1f + (size_t)ch * UN * UN;
  const float* w2c = w2f + (size_t)ch * UN * UN;
  const float* w3c = w3f + (size_t)ch * FOUT * UN;
  const float* b0c = b0 + ch * UN;
  const float* b1c = b1 + ch * UN;
  const float* b2c = b2 + ch * UN;
  const float* b3c = b3 + ch * FOUT;

  // stage x tile (fp32 -> bf16) into actA, frag order with nk=2
  {
    const float* xs = x + (size_t)(ch * SEC + row0) * FIN;
    const int row = (w >> 1) * 16 + l15;
    const int col = (w & 1) * 32 + l4 * 8;
    store_cvt8(actA + w * 1024 + l * 16, xs + row * FIN + col);
  }
  __syncthreads();

  run_layer<64, 512, WSPATH>(w0b, w0c, b0c, actA, actB, nullptr, wst, w, l, l15, l4, wm, wn);
  __syncthreads();
  run_layer<512, 512, WSPATH>(w1b, w1c, b1c, actB, actA, nullptr, wst, w, l, l15, l4, wm, wn);
  __syncthreads();
  run_layer<512, 512, WSPATH>(w2b, w2c, b2c, actA, actB, nullptr, wst, w, l, l15, l4, wm, wn);
  __syncthreads();
  run_layer<512, 64, WSPATH>(w3b, w3c, b3c, actB, nullptr,
                             out + (size_t)(ch * SEC + row0) * FOUT, wst,
                             w, l, l15, l4, wm, wn);
}

// one-shot fp32 -> bf16 weight conversion into d_ws (layout: w0|w1|w2|w3 flat)
__global__ void cvt_weights(const float* __restrict__ w0, const float* __restrict__ w1,
                            const float* __restrict__ w2, const float* __restrict__ w3,
                            bf16* __restrict__ o)
{
  const int n0 = CH * UN * FIN;   // 262144
  const int n1 = CH * UN * UN;    // 2097152
  const int total = 2 * n0 + 2 * n1;
  for (int i4 = blockIdx.x * blockDim.x + threadIdx.x; i4 < total / 4;
       i4 += gridDim.x * blockDim.x) {
    const int idx = i4 * 4;
    const float* src; int off;
    if (idx < n0)                { src = w0; off = idx; }
    else if (idx < n0 + n1)      { src = w1; off = idx - n0; }
    else if (idx < n0 + 2 * n1)  { src = w2; off = idx - n0 - n1; }
    else                         { src = w3; off = idx - n0 - 2 * n1; }
    const f32x4 v = *(const f32x4*)(src + off);
    bf16x4 r;
    r[0] = (bf16)v[0]; r[1] = (bf16)v[1]; r[2] = (bf16)v[2]; r[3] = (bf16)v[3];
    *(bf16x4*)(o + idx) = r;
  }
}

extern "C" void kernel_launch(void* const* d_in, const int* in_sizes, int n_in,
                              void* d_out, int out_size, void* d_ws, size_t ws_size,
                              hipStream_t stream)
{
  const float* x  = (const float*)d_in[0];
  const float* w0 = (const float*)d_in[1];
  const float* w1 = (const float*)d_in[2];
  const float* w2 = (const float*)d_in[3];
  const float* w3 = (const float*)d_in[4];
  const float* b0 = (const float*)d_in[5];
  const float* b1 = (const float*)d_in[6];
  const float* b2 = (const float*)d_in[7];
  const float* b3 = (const float*)d_in[8];
  float* out = (float*)d_out;

  const int grid = CH * (SEC / BM);            // 4096 blocks
  const size_t wbytes = (size_t)(2 * CH * UN * FIN + 2 * CH * UN * UN) * 2;  // 9437184

  if (ws_size >= wbytes) {
    bf16* wb = (bf16*)d_ws;
    hipLaunchKernelGGL(cvt_weights, dim3(2048), dim3(256), 0, stream, w0, w1, w2, w3, wb);
    hipFuncSetAttribute(reinterpret_cast<const void*>(mlp_fused<true>),
                        hipFuncAttributeMaxDynamicSharedMemorySize, 163840);
    hipLaunchKernelGGL(mlp_fused<true>, dim3(grid), dim3(512), 163840, stream,
                       x, w0, w1, w2, w3, b0, b1, b2, b3, wb, out);
  } else {
    hipFuncSetAttribute(reinterpret_cast<const void*>(mlp_fused<false>),
                        hipFuncAttributeMaxDynamicSharedMemorySize, 163840);
    hipLaunchKernelGGL(mlp_fused<false>, dim3(grid), dim3(512), 163840, stream,
                       x, w0, w1, w2, w3, b0, b1, b2, b3, (const bf16*)nullptr, out);
  }
}

// Round 2
// 725.622 us; speedup vs baseline: 1.1831x; 1.1831x over previous
//
#include <hip/hip_runtime.h>
#include <hip/hip_bf16.h>

#define CH 8
#define SEC 32768
#define FIN 64
#define FOUT 64
#define UN 512
#define BM 64

typedef __bf16 bf16;
typedef bf16 bf16x8 __attribute__((ext_vector_type(8)));
typedef bf16 bf16x4 __attribute__((ext_vector_type(4)));
typedef float f32x4 __attribute__((ext_vector_type(4)));

// async global->LDS, 16B per lane; LDS dest is wave-uniform base + lane*16
__device__ __forceinline__ void gload_lds16(const void* g, void* l) {
  __builtin_amdgcn_global_load_lds(
      (const __attribute__((address_space(1))) void*)g,
      (__attribute__((address_space(3))) void*)l, 16, 0, 0);
}

// load 8 consecutive fp32, convert to bf16x8, store 16B to LDS
__device__ __forceinline__ void store_cvt8(void* dst, const float* __restrict__ src) {
  f32x4 u0 = *(const f32x4*)src;
  f32x4 u1 = *(const f32x4*)(src + 4);
  bf16x8 v;
  v[0] = (bf16)u0[0]; v[1] = (bf16)u0[1]; v[2] = (bf16)u0[2]; v[3] = (bf16)u0[3];
  v[4] = (bf16)u1[0]; v[5] = (bf16)u1[1]; v[6] = (bf16)u1[2]; v[7] = (bf16)u1[3];
  *(bf16x8*)dst = v;
}

// ---------------------------------------------------------------------------
// Main layer: [64 x K] (LDS actIn, frag order) x [512 x K]^T -> [64 x 512].
// Wave w (0..7) owns output cols w*64 .. w*64+63 (all 64 rows): 4x4 MFMA tiles.
// Weight k-panels double-buffered in `wreg` (32KB each half); the SAME region
// receives the epilogue output (safe: epilogue starts after the K-loop's
// final barrier, when all wst reads are done).
// Pipeline: prefetch panel ks+1 BEFORE computing panel ks; ONE barrier/K-step.
// ---------------------------------------------------------------------------
template<int K, bool WSPATH>
__device__ __forceinline__ void run_main_layer(
    const bf16* __restrict__ wb, const float* __restrict__ wf,
    const float* __restrict__ bias,
    const char* __restrict__ actIn, char* __restrict__ wreg,
    int w, int l, int l15, int l4)
{
  constexpr int NKS = K / 32;

  auto stage = [&](int ks) {
    char* buf = wreg + (ks & 1) * 32768;
#pragma unroll
    for (int i = 0; i < 4; ++i) {
      const int f = w * 4 + i;  // frag = 16 cols; wave stages its own cols
      if constexpr (WSPATH)
        gload_lds16(wb + (size_t)(f * 16 + l15) * K + ks * 32 + l4 * 8,
                    buf + f * 1024);
      else
        store_cvt8(buf + f * 1024 + l * 16,
                   wf + (size_t)(f * 16 + l15) * K + ks * 32 + l4 * 8);
    }
  };

  f32x4 acc[4][4];
#pragma unroll
  for (int mt = 0; mt < 4; ++mt)
#pragma unroll
    for (int nt = 0; nt < 4; ++nt)
      acc[mt][nt] = f32x4{0.f, 0.f, 0.f, 0.f};

  stage(0);
  __syncthreads();  // panel 0 ready; also makes prior epilogue/x-stage visible

  for (int ks = 0; ks < NKS; ++ks) {
    if (ks + 1 < NKS) stage(ks + 1);  // prefetch into other half
    const char* wbuf = wreg + (ks & 1) * 32768;
    bf16x8 a[4], b[4];
#pragma unroll
    for (int mt = 0; mt < 4; ++mt)
      a[mt] = *(const bf16x8*)(actIn + (mt * NKS + ks) * 1024 + l * 16);
#pragma unroll
    for (int nt = 0; nt < 4; ++nt)
      b[nt] = *(const bf16x8*)(wbuf + (w * 4 + nt) * 1024 + l * 16);
#pragma unroll
    for (int mt = 0; mt < 4; ++mt)
#pragma unroll
      for (int nt = 0; nt < 4; ++nt)
        acc[mt][nt] = __builtin_amdgcn_mfma_f32_16x16x32_bf16(a[mt], b[nt], acc[mt][nt], 0, 0, 0);
    __syncthreads();  // prefetch landed (vmcnt drain AFTER compute) + wst reads done
  }

  // epilogue: bias+relu -> wreg in next layer's frag order (next NKS = 16)
#pragma unroll
  for (int mt = 0; mt < 4; ++mt) {
#pragma unroll
    for (int nt = 0; nt < 4; ++nt) {
      const int col = w * 64 + nt * 16 + l15;  // = next layer's k
      const float bv = bias[col];
      const int addr = mt * 16384 + (col >> 5) * 1024 + ((col >> 3) & 3) * 256
                     + (col & 7) * 2 + l4 * 64;
#pragma unroll
      for (int r = 0; r < 4; ++r) {
        float v = acc[mt][nt][r] + bv;
        v = v > 0.f ? v : 0.f;
        *(bf16*)(wreg + addr + r * 16) = (bf16)v;
      }
    }
  }
}

// ---------------------------------------------------------------------------
// Final layer: [64 x 512] x [64 x 512]^T -> [64 x 64] fp32 to global (no relu)
// Wave: wn3 = w&3 (n-tile), wm3 = w>>2 (m-half, 2 m-tiles). Waves 0-3 stage.
// ---------------------------------------------------------------------------
template<bool WSPATH>
__device__ __forceinline__ void run_final_layer(
    const bf16* __restrict__ wb, const float* __restrict__ wf,
    const float* __restrict__ bias,
    const char* __restrict__ actIn, char* __restrict__ wreg,
    float* __restrict__ gout,
    int w, int l, int l15, int l4)
{
  constexpr int NKS = 16;
  const int wn3 = w & 3, wm3 = w >> 2;

  auto stage = [&](int ks) {
    if (w < 4) {
      char* buf = wreg + (ks & 1) * 4096;
      if constexpr (WSPATH)
        gload_lds16(wb + (size_t)(w * 16 + l15) * 512 + ks * 32 + l4 * 8,
                    buf + w * 1024);
      else
        store_cvt8(buf + w * 1024 + l * 16,
                   wf + (size_t)(w * 16 + l15) * 512 + ks * 32 + l4 * 8);
    }
  };

  f32x4 acc[2];
  acc[0] = f32x4{0.f, 0.f, 0.f, 0.f};
  acc[1] = f32x4{0.f, 0.f, 0.f, 0.f};

  stage(0);
  __syncthreads();

  for (int ks = 0; ks < NKS; ++ks) {
    if (ks + 1 < NKS) stage(ks + 1);
    const char* wbuf = wreg + (ks & 1) * 4096;
    const bf16x8 b  = *(const bf16x8*)(wbuf + wn3 * 1024 + l * 16);
    const bf16x8 a0 = *(const bf16x8*)(actIn + ((wm3 * 2 + 0) * NKS + ks) * 1024 + l * 16);
    const bf16x8 a1 = *(const bf16x8*)(actIn + ((wm3 * 2 + 1) * NKS + ks) * 1024 + l * 16);
    acc[0] = __builtin_amdgcn_mfma_f32_16x16x32_bf16(a0, b, acc[0], 0, 0, 0);
    acc[1] = __builtin_amdgcn_mfma_f32_16x16x32_bf16(a1, b, acc[1], 0, 0, 0);
    __syncthreads();
  }

  const int col = wn3 * 16 + l15;
  const float bv = bias[col];
#pragma unroll
  for (int i = 0; i < 2; ++i) {
    const int rowl = wm3 * 32 + i * 16 + l4 * 4;
#pragma unroll
    for (int r = 0; r < 4; ++r)
      gout[(size_t)(rowl + r) * FOUT + col] = acc[i][r] + bv;
  }
}

template<bool WSPATH>
__global__ __launch_bounds__(512, 2) void mlp_fused(
    const float* __restrict__ x,
    const float* __restrict__ w0f, const float* __restrict__ w1f,
    const float* __restrict__ w2f, const float* __restrict__ w3f,
    const float* __restrict__ b0, const float* __restrict__ b1,
    const float* __restrict__ b2, const float* __restrict__ b3,
    const bf16* __restrict__ wbase,
    float* __restrict__ out)
{
  extern __shared__ char smem[];
  char* R0 = smem;           // 64 KiB
  char* R1 = smem + 65536;   // 64 KiB

  const int tid = threadIdx.x;
  const int w = tid >> 6, l = tid & 63;
  const int l15 = l & 15, l4 = l >> 4;

  // XCD-chunked swizzle: each XCD owns one channel -> weights L2-resident
  const int wg = (blockIdx.x & 7) * 512 + (blockIdx.x >> 3);
  const int ch = wg >> 9;
  const int row0 = (wg & 511) * BM;

  const bf16* w0b = wbase + (size_t)ch * UN * FIN;
  const bf16* w1b = wbase + CH * UN * FIN + (size_t)ch * UN * UN;
  const bf16* w2b = wbase + CH * UN * FIN + CH * UN * UN + (size_t)ch * UN * UN;
  const bf16* w3b = wbase + CH * UN * FIN + 2 * CH * UN * UN + (size_t)ch * FOUT * UN;
  const float* w0c = w0f + (size_t)ch * UN * FIN;
  const float* w1c = w1f + (size_t)ch * UN * UN;
  const float* w2c = w2f + (size_t)ch * UN * UN;
  const float* w3c = w3f + (size_t)ch * FOUT * UN;
  const float* b0c = b0 + ch * UN;
  const float* b1c = b1 + ch * UN;
  const float* b2c = b2 + ch * UN;
  const float* b3c = b3 + ch * FOUT;

  // stage x tile (fp32 -> bf16) into R0, frag order with NKS=2
  {
    const float* xs = x + (size_t)(ch * SEC + row0) * FIN;
    store_cvt8(R0 + w * 1024 + l * 16,
               xs + ((w >> 1) * 16 + l15) * FIN + (w & 1) * 32 + l4 * 8);
  }
  // no barrier needed: run_main_layer's prologue barrier covers visibility

  run_main_layer<64,  WSPATH>(w0b, w0c, b0c, R0, R1, w, l, l15, l4);
  run_main_layer<512, WSPATH>(w1b, w1c, b1c, R1, R0, w, l, l15, l4);
  run_main_layer<512, WSPATH>(w2b, w2c, b2c, R0, R1, w, l, l15, l4);
  run_final_layer<WSPATH>(w3b, w3c, b3c, R1, R0,
                          out + (size_t)(ch * SEC + row0) * FOUT,
                          w, l, l15, l4);
}

// one-shot fp32 -> bf16 weight conversion into d_ws (layout: w0|w1|w2|w3 flat)
__global__ void cvt_weights(const float* __restrict__ w0, const float* __restrict__ w1,
                            const float* __restrict__ w2, const float* __restrict__ w3,
                            bf16* __restrict__ o)
{
  const int n0 = CH * UN * FIN;   // 262144
  const int n1 = CH * UN * UN;    // 2097152
  const int total = 2 * n0 + 2 * n1;
  for (int i4 = blockIdx.x * blockDim.x + threadIdx.x; i4 < total / 4;
       i4 += gridDim.x * blockDim.x) {
    const int idx = i4 * 4;
    const float* src; int off;
    if (idx < n0)                { src = w0; off = idx; }
    else if (idx < n0 + n1)      { src = w1; off = idx - n0; }
    else if (idx < n0 + 2 * n1)  { src = w2; off = idx - n0 - n1; }
    else                         { src = w3; off = idx - n0 - 2 * n1; }
    const f32x4 v = *(const f32x4*)(src + off);
    bf16x4 r;
    r[0] = (bf16)v[0]; r[1] = (bf16)v[1]; r[2] = (bf16)v[2]; r[3] = (bf16)v[3];
    *(bf16x4*)(o + idx) = r;
  }
}

extern "C" void kernel_launch(void* const* d_in, const int* in_sizes, int n_in,
                              void* d_out, int out_size, void* d_ws, size_t ws_size,
                              hipStream_t stream)
{
  const float* x  = (const float*)d_in[0];
  const float* w0 = (const float*)d_in[1];
  const float* w1 = (const float*)d_in[2];
  const float* w2 = (const float*)d_in[3];
  const float* w3 = (const float*)d_in[4];
  const float* b0 = (const float*)d_in[5];
  const float* b1 = (const float*)d_in[6];
  const float* b2 = (const float*)d_in[7];
  const float* b3 = (const float*)d_in[8];
  float* out = (float*)d_out;

  const int grid = CH * (SEC / BM);            // 4096 blocks
  const size_t wbytes = (size_t)(2 * CH * UN * FIN + 2 * CH * UN * UN) * 2;  // 9437184

  if (ws_size >= wbytes) {
    bf16* wb = (bf16*)d_ws;
    hipLaunchKernelGGL(cvt_weights, dim3(2048), dim3(256), 0, stream, w0, w1, w2, w3, wb);
    hipFuncSetAttribute(reinterpret_cast<const void*>(mlp_fused<true>),
                        hipFuncAttributeMaxDynamicSharedMemorySize, 131072);
    hipLaunchKernelGGL(mlp_fused<true>, dim3(grid), dim3(512), 131072, stream,
                       x, w0, w1, w2, w3, b0, b1, b2, b3, wb, out);
  } else {
    hipFuncSetAttribute(reinterpret_cast<const void*>(mlp_fused<false>),
                        hipFuncAttributeMaxDynamicSharedMemorySize, 131072);
    hipLaunchKernelGGL(mlp_fused<false>, dim3(grid), dim3(512), 131072, stream,
                       x, w0, w1, w2, w3, b0, b1, b2, b3, (const bf16*)nullptr, out);
  }
}

// Round 3
// 625.095 us; speedup vs baseline: 1.3734x; 1.1608x over previous
//
#include <hip/hip_runtime.h>
#include <hip/hip_bf16.h>

#define CH 8
#define SEC 32768
#define FIN 64
#define FOUT 64
#define UN 512
#define BM 64

typedef __bf16 bf16;
typedef bf16 bf16x8 __attribute__((ext_vector_type(8)));
typedef bf16 bf16x4 __attribute__((ext_vector_type(4)));
typedef float f32x4 __attribute__((ext_vector_type(4)));

// load 8 consecutive fp32 and convert to bf16x8 (register path)
__device__ __forceinline__ bf16x8 cvt8(const float* __restrict__ src) {
  f32x4 u0 = *(const f32x4*)src;
  f32x4 u1 = *(const f32x4*)(src + 4);
  bf16x8 v;
  v[0] = (bf16)u0[0]; v[1] = (bf16)u0[1]; v[2] = (bf16)u0[2]; v[3] = (bf16)u0[3];
  v[4] = (bf16)u1[0]; v[5] = (bf16)u1[1]; v[6] = (bf16)u1[2]; v[7] = (bf16)u1[3];
  return v;
}

// fp32 -> bf16x8 -> LDS 16B (x-tile staging)
__device__ __forceinline__ void store_cvt8(void* dst, const float* __restrict__ src) {
  *(bf16x8*)dst = cvt8(src);
}

// ---------------------------------------------------------------------------
// Main layer: [64 x K] (LDS act, frag order) x [512 x K]^T -> [64 x 512],
// bias+relu, written back IN-PLACE into `act` in next layer's frag order.
// Weights are NOT staged in LDS: each wave loads its own B-fragments straight
// into registers (waves read disjoint columns, so block-level L2 traffic is
// identical to LDS staging) -> ZERO barriers inside the K-loop; waves run
// fully desynchronized and latency is hidden by ILP + 4 waves/SIMD.
// Wave w owns output cols w*64 .. w*64+63 (4x4 MFMA tiles over 64 rows).
// ---------------------------------------------------------------------------
template<int K, bool WSPATH>
__device__ __forceinline__ void run_main_layer(
    const bf16* __restrict__ wb, const float* __restrict__ wf,
    const float* __restrict__ bias, char* __restrict__ act,
    int w, int l, int l15, int l4)
{
  constexpr int NKS = K / 32;
  const int col0 = w * 64;

  // per-nt row base pointers; ks advances via compile-time immediate offsets
  const bf16*  wr[4];
  const float* wrf[4];
#pragma unroll
  for (int nt = 0; nt < 4; ++nt) {
    if constexpr (WSPATH) wr[nt]  = wb + (size_t)(col0 + nt * 16 + l15) * K + l4 * 8;
    else                  wrf[nt] = wf + (size_t)(col0 + nt * 16 + l15) * K + l4 * 8;
  }

  f32x4 acc[4][4];
#pragma unroll
  for (int mt = 0; mt < 4; ++mt)
#pragma unroll
    for (int nt = 0; nt < 4; ++nt)
      acc[mt][nt] = f32x4{0.f, 0.f, 0.f, 0.f};

#pragma unroll 2
  for (int ks = 0; ks < NKS; ++ks) {
    bf16x8 a[4], b[4];
#pragma unroll
    for (int nt = 0; nt < 4; ++nt) {
      if constexpr (WSPATH) b[nt] = *(const bf16x8*)(wr[nt] + ks * 32);
      else                  b[nt] = cvt8(wrf[nt] + ks * 32);
    }
#pragma unroll
    for (int mt = 0; mt < 4; ++mt)
      a[mt] = *(const bf16x8*)(act + (mt * NKS + ks) * 1024 + l * 16);
    __builtin_amdgcn_s_setprio(1);
#pragma unroll
    for (int mt = 0; mt < 4; ++mt)
#pragma unroll
      for (int nt = 0; nt < 4; ++nt)
        acc[mt][nt] = __builtin_amdgcn_mfma_f32_16x16x32_bf16(a[mt], b[nt], acc[mt][nt], 0, 0, 0);
    __builtin_amdgcn_s_setprio(0);
  }

  __syncthreads();  // all waves done reading act for this layer

  // epilogue: bias+relu -> act, next layer's frag order (next NKS = 16)
#pragma unroll
  for (int nt = 0; nt < 4; ++nt) {
    const int col = col0 + nt * 16 + l15;       // = next layer's k index
    const float bv = bias[col];
    const int base = (col >> 5) * 1024 + ((col >> 3) & 3) * 256 + (col & 7) * 2 + l4 * 64;
#pragma unroll
    for (int mt = 0; mt < 4; ++mt)
#pragma unroll
      for (int r = 0; r < 4; ++r) {
        float v = acc[mt][nt][r] + bv;
        v = v > 0.f ? v : 0.f;
        *(bf16*)(act + mt * 16384 + base + r * 16) = (bf16)v;
      }
  }
  __syncthreads();  // act ready for next layer
}

// ---------------------------------------------------------------------------
// Final layer: [64 x 512] x [64 x 512]^T -> [64 x 64] fp32 to global, no relu.
// Wave w: m-tile = w>>1, n-frags {(w&1)*2, (w&1)*2+1}. No barriers needed.
// ---------------------------------------------------------------------------
template<bool WSPATH>
__device__ __forceinline__ void run_final_layer(
    const bf16* __restrict__ wb, const float* __restrict__ wf,
    const float* __restrict__ bias, const char* __restrict__ act,
    float* __restrict__ gout,
    int w, int l, int l15, int l4)
{
  constexpr int NKS = 16;
  const int mt = w >> 1;
  const int nb = (w & 1) * 2;

  const bf16*  wr[2];
  const float* wrf[2];
#pragma unroll
  for (int i = 0; i < 2; ++i) {
    if constexpr (WSPATH) wr[i]  = wb + (size_t)((nb + i) * 16 + l15) * UN + l4 * 8;
    else                  wrf[i] = wf + (size_t)((nb + i) * 16 + l15) * UN + l4 * 8;
  }

  f32x4 acc[2];
  acc[0] = f32x4{0.f, 0.f, 0.f, 0.f};
  acc[1] = f32x4{0.f, 0.f, 0.f, 0.f};

#pragma unroll 4
  for (int ks = 0; ks < NKS; ++ks) {
    bf16x8 b0, b1;
    if constexpr (WSPATH) { b0 = *(const bf16x8*)(wr[0] + ks * 32);
                            b1 = *(const bf16x8*)(wr[1] + ks * 32); }
    else                  { b0 = cvt8(wrf[0] + ks * 32);
                            b1 = cvt8(wrf[1] + ks * 32); }
    const bf16x8 a = *(const bf16x8*)(act + (mt * NKS + ks) * 1024 + l * 16);
    acc[0] = __builtin_amdgcn_mfma_f32_16x16x32_bf16(a, b0, acc[0], 0, 0, 0);
    acc[1] = __builtin_amdgcn_mfma_f32_16x16x32_bf16(a, b1, acc[1], 0, 0, 0);
  }

#pragma unroll
  for (int i = 0; i < 2; ++i) {
    const int col = (nb + i) * 16 + l15;
    const float bv = bias[col];
#pragma unroll
    for (int r = 0; r < 4; ++r)
      gout[(size_t)(mt * 16 + l4 * 4 + r) * FOUT + col] = acc[i][r] + bv;
  }
}

template<bool WSPATH>
__global__ __launch_bounds__(512, 4) void mlp_fused(
    const float* __restrict__ x,
    const float* __restrict__ w0f, const float* __restrict__ w1f,
    const float* __restrict__ w2f, const float* __restrict__ w3f,
    const float* __restrict__ b0, const float* __restrict__ b1,
    const float* __restrict__ b2, const float* __restrict__ b3,
    const bf16* __restrict__ wbase,
    float* __restrict__ out)
{
  extern __shared__ char smem[];
  char* act = smem;  // 64 KiB, in-place activations, frag order

  const int tid = threadIdx.x;
  const int w = tid >> 6, l = tid & 63;
  const int l15 = l & 15, l4 = l >> 4;

  // XCD-chunked swizzle: each XCD owns one channel -> weights L2-resident
  const int wg = (blockIdx.x & 7) * 512 + (blockIdx.x >> 3);
  const int ch = wg >> 9;
  const int row0 = (wg & 511) * BM;

  const bf16* w0b = wbase + (size_t)ch * UN * FIN;
  const bf16* w1b = wbase + CH * UN * FIN + (size_t)ch * UN * UN;
  const bf16* w2b = wbase + CH * UN * FIN + CH * UN * UN + (size_t)ch * UN * UN;
  const bf16* w3b = wbase + CH * UN * FIN + 2 * CH * UN * UN + (size_t)ch * FOUT * UN;
  const float* w0c = w0f + (size_t)ch * UN * FIN;
  const float* w1c = w1f + (size_t)ch * UN * UN;
  const float* w2c = w2f + (size_t)ch * UN * UN;
  const float* w3c = w3f + (size_t)ch * FOUT * UN;
  const float* b0c = b0 + ch * UN;
  const float* b1c = b1 + ch * UN;
  const float* b2c = b2 + ch * UN;
  const float* b3c = b3 + ch * FOUT;

  // stage x tile (fp32 -> bf16) into act, frag order with NKS=2
  {
    const float* xs = x + (size_t)(ch * SEC + row0) * FIN;
    store_cvt8(act + w * 1024 + l * 16,
               xs + ((w >> 1) * 16 + l15) * FIN + (w & 1) * 32 + l4 * 8);
  }
  __syncthreads();

  run_main_layer<64,  WSPATH>(w0b, w0c, b0c, act, w, l, l15, l4);
  run_main_layer<512, WSPATH>(w1b, w1c, b1c, act, w, l, l15, l4);
  run_main_layer<512, WSPATH>(w2b, w2c, b2c, act, w, l, l15, l4);
  run_final_layer<WSPATH>(w3b, w3c, b3c, act,
                          out + (size_t)(ch * SEC + row0) * FOUT,
                          w, l, l15, l4);
}

// one-shot fp32 -> bf16 weight conversion into d_ws (layout: w0|w1|w2|w3 flat)
__global__ void cvt_weights(const float* __restrict__ w0, const float* __restrict__ w1,
                            const float* __restrict__ w2, const float* __restrict__ w3,
                            bf16* __restrict__ o)
{
  const int n0 = CH * UN * FIN;   // 262144
  const int n1 = CH * UN * UN;    // 2097152
  const int total = 2 * n0 + 2 * n1;
  for (int i4 = blockIdx.x * blockDim.x + threadIdx.x; i4 < total / 4;
       i4 += gridDim.x * blockDim.x) {
    const int idx = i4 * 4;
    const float* src; int off;
    if (idx < n0)                { src = w0; off = idx; }
    else if (idx < n0 + n1)      { src = w1; off = idx - n0; }
    else if (idx < n0 + 2 * n1)  { src = w2; off = idx - n0 - n1; }
    else                         { src = w3; off = idx - n0 - 2 * n1; }
    const f32x4 v = *(const f32x4*)(src + off);
    bf16x4 r;
    r[0] = (bf16)v[0]; r[1] = (bf16)v[1]; r[2] = (bf16)v[2]; r[3] = (bf16)v[3];
    *(bf16x4*)(o + idx) = r;
  }
}

extern "C" void kernel_launch(void* const* d_in, const int* in_sizes, int n_in,
                              void* d_out, int out_size, void* d_ws, size_t ws_size,
                              hipStream_t stream)
{
  const float* x  = (const float*)d_in[0];
  const float* w0 = (const float*)d_in[1];
  const float* w1 = (const float*)d_in[2];
  const float* w2 = (const float*)d_in[3];
  const float* w3 = (const float*)d_in[4];
  const float* b0 = (const float*)d_in[5];
  const float* b1 = (const float*)d_in[6];
  const float* b2 = (const float*)d_in[7];
  const float* b3 = (const float*)d_in[8];
  float* out = (float*)d_out;

  const int grid = CH * (SEC / BM);            // 4096 blocks
  const size_t wbytes = (size_t)(2 * CH * UN * FIN + 2 * CH * UN * UN) * 2;  // 9437184

  if (ws_size >= wbytes) {
    bf16* wb = (bf16*)d_ws;
    hipLaunchKernelGGL(cvt_weights, dim3(2048), dim3(256), 0, stream, w0, w1, w2, w3, wb);
    hipFuncSetAttribute(reinterpret_cast<const void*>(mlp_fused<true>),
                        hipFuncAttributeMaxDynamicSharedMemorySize, 65536);
    hipLaunchKernelGGL(mlp_fused<true>, dim3(grid), dim3(512), 65536, stream,
                       x, w0, w1, w2, w3, b0, b1, b2, b3, wb, out);
  } else {
    hipFuncSetAttribute(reinterpret_cast<const void*>(mlp_fused<false>),
                        hipFuncAttributeMaxDynamicSharedMemorySize, 65536);
    hipLaunchKernelGGL(mlp_fused<false>, dim3(grid), dim3(512), 65536, stream,
                       x, w0, w1, w2, w3, b0, b1, b2, b3, (const bf16*)nullptr, out);
  }
}